// Round 1
// baseline (483.584 us; speedup 1.0000x reference)
//
#include <hip/hip_runtime.h>
#include <stdint.h>

#define N_NODES 100000
#define N_EDGES 1600000
#define NFEAT 256
#define NHID 64
#define N_ELEMS (N_NODES * NHID)   // 6,400,000
#define NBLK 391                   // ceil(N_NODES/256) for scan kernels

// Bucketed binning (R10): row-buckets of 1024 rows.
#define BSHIFT 10
#define NBUCK 98                   // ceil(100000/1024)
#define CHUNK 4096                 // edges per bucket_kernel block
#define NBBLK ((N_EDGES + CHUNK - 1) / CHUNK)   // 391
#define EPX (N_EDGES / 8)          // 200000 edges per XCD span in place_kernel
#define PBLK ((EPX + 255) / 256)   // 782

// Config (validated R6/R7): inputs f32, output f32, dropout = JAX partitionable
// threefry (key=(0,42), counter (0,i), bits = o0^o1).
//
// R7: feature-space f32 atomics hit TCC ceiling (303G/s) -> CSR + gather (R8).
// R8: bin_kernel latency-bound -> R9 one thread per edge + bf16 support.
// R10: bin_kernel was write-amplification-bound (WRITE_SIZE 100MB for a
//      12.8MB output: random 8B scatter dirties a full 64B line each).
//      Replaced by two-pass bucketed sort:
//        bucket_kernel: LDS-staged scatter into 98 row-buckets; per-block
//          per-bucket ranges are contiguous (~336B) -> ~1.2x line amp.
//        place_kernel: per-row scatter now confined to ~130KB bucket regions
//          (L2-resident); XCD-span swizzle keeps each region's lines on one
//          XCD's L2 so lines fill before write-back.
//
// ws layout (39.6 MB + 512B):
//   sums[128] f32 | scaleshift[128] f32 | cnt[100000] i32 | rowptr[100002] i32
//   | cursor[100000] i32 | bsum[512] i32 | bcur[128] i32 | wt[16384] ushort
//   | agg[6.4M] f32 | sorted[1.6M] int2
// support[6.4M] bf16 staged in d_out (dead before apply overwrites).
// bucketed[1.6M] int2 aliases agg[0..3.2M] (dead until gather writes agg).

typedef __attribute__((ext_vector_type(8))) short bf16x8;
typedef __attribute__((ext_vector_type(4))) float f32x4;

__device__ __forceinline__ unsigned short f2bf(float f) {
    uint32_t u = __float_as_uint(f);
    u += 0x7FFFu + ((u >> 16) & 1u);   // RNE
    return (unsigned short)(u >> 16);
}
__device__ __forceinline__ float bf2f(unsigned short u) {
    return __uint_as_float(((uint32_t)u) << 16);
}

// ---------------------------------------------------------------------------
// W^T prep: wt[n][k] = bf16(W[k][n])
// ---------------------------------------------------------------------------
__global__ __launch_bounds__(256) void wtprep_kernel(const float* __restrict__ W,
                                                     unsigned short* __restrict__ wt) {
    int i = blockIdx.x * 256 + threadIdx.x;
    if (i < NFEAT * NHID) {
        int k = i >> 6, n = i & 63;
        wt[n * NFEAT + k] = f2bf(W[i]);
    }
}

// ---------------------------------------------------------------------------
// GEMM (MFMA bf16): support[N x 64] = x[N x 256] @ W[256 x 64], bf16 out.
// 64-row tile, whole K=256 in LDS, 4 waves x 4 n-tiles of 16x16x32 MFMA.
// ---------------------------------------------------------------------------
__global__ __launch_bounds__(256) void gemm_kernel(const float* __restrict__ x,
                                                   const unsigned short* __restrict__ wt,
                                                   unsigned short* __restrict__ support) {
    __shared__ unsigned short Abf[64][264];  // row stride 528B, 16B-aligned
    __shared__ unsigned short Bt[64][264];   // Bt[n][k]
    const int t = threadIdx.x;
    const int row0 = blockIdx.x * 64;

    {
        const int r = t >> 6;
        const int c4 = t & 63;
        #pragma unroll
        for (int rr = 0; rr < 16; rr++) {
            int lr_ = rr * 4 + r;
            int gr = row0 + lr_;
            float4 v = make_float4(0.f, 0.f, 0.f, 0.f);
            if (gr < N_NODES) v = *(const float4*)&x[(size_t)gr * NFEAT + c4 * 4];
            ushort4 u;
            u.x = f2bf(v.x); u.y = f2bf(v.y); u.z = f2bf(v.z); u.w = f2bf(v.w);
            *(ushort4*)&Abf[lr_][c4 * 4] = u;
        }
    }
    {
        const int rB = t >> 5;
        const int ch = t & 31;
        #pragma unroll
        for (int rr = 0; rr < 8; rr++) {
            int n = rr * 8 + rB;
            uint4 v = *(const uint4*)&wt[n * NFEAT + ch * 8];
            *(uint4*)&Bt[n][ch * 8] = v;
        }
    }
    __syncthreads();

    const int lane = t & 63;
    const int w = t >> 6;
    const int m = lane & 15;
    const int q = lane >> 4;
    f32x4 acc0 = {0.f, 0.f, 0.f, 0.f};
    f32x4 acc1 = acc0, acc2 = acc0, acc3 = acc0;

    #pragma unroll
    for (int ks = 0; ks < NFEAT; ks += 32) {
        bf16x8 af = *(const bf16x8*)&Abf[w * 16 + m][ks + q * 8];
        bf16x8 b0 = *(const bf16x8*)&Bt[ 0 + m][ks + q * 8];
        bf16x8 b1 = *(const bf16x8*)&Bt[16 + m][ks + q * 8];
        bf16x8 b2 = *(const bf16x8*)&Bt[32 + m][ks + q * 8];
        bf16x8 b3 = *(const bf16x8*)&Bt[48 + m][ks + q * 8];
        acc0 = __builtin_amdgcn_mfma_f32_16x16x32_bf16(af, b0, acc0, 0, 0, 0);
        acc1 = __builtin_amdgcn_mfma_f32_16x16x32_bf16(af, b1, acc1, 0, 0, 0);
        acc2 = __builtin_amdgcn_mfma_f32_16x16x32_bf16(af, b2, acc2, 0, 0, 0);
        acc3 = __builtin_amdgcn_mfma_f32_16x16x32_bf16(af, b3, acc3, 0, 0, 0);
    }

    // C/D layout: row = q*4 + reg, col = nt*16 + m
    #pragma unroll
    for (int reg = 0; reg < 4; reg++) {
        int grow = row0 + w * 16 + q * 4 + reg;
        if (grow < N_NODES) {
            support[(size_t)grow * NHID +  0 + m] = f2bf(acc0[reg]);
            support[(size_t)grow * NHID + 16 + m] = f2bf(acc1[reg]);
            support[(size_t)grow * NHID + 32 + m] = f2bf(acc2[reg]);
            support[(size_t)grow * NHID + 48 + m] = f2bf(acc3[reg]);
        }
    }
}

// ---------------------------------------------------------------------------
// CSR step 1: histogram. One thread per edge (pure TLP, fire-and-forget).
// ---------------------------------------------------------------------------
__global__ __launch_bounds__(256) void hist_kernel(const int* __restrict__ row,
                                                   int* __restrict__ cnt) {
    int e = blockIdx.x * 256 + threadIdx.x;
    if (e < N_EDGES) atomicAdd(&cnt[row[e]], 1);
}

// ---------------------------------------------------------------------------
// CSR step 2a: per-block exclusive scan + block sums.
// ---------------------------------------------------------------------------
__global__ __launch_bounds__(256) void scan1_kernel(const int* __restrict__ cnt,
                                                    int* __restrict__ rowptr,
                                                    int* __restrict__ bsum) {
    __shared__ int s[256];
    const int t = threadIdx.x;
    const int i = blockIdx.x * 256 + t;
    int v = (i < N_NODES) ? cnt[i] : 0;
    s[t] = v;
    __syncthreads();
    #pragma unroll
    for (int off = 1; off < 256; off <<= 1) {
        int u = (t >= off) ? s[t - off] : 0;
        __syncthreads();
        s[t] += u;
        __syncthreads();
    }
    if (i < N_NODES) rowptr[i] = s[t] - v;
    if (t == 255) bsum[blockIdx.x] = s[t];
}

// ---------------------------------------------------------------------------
// CSR step 2b: exclusive scan of NBLK block sums (single block).
// ---------------------------------------------------------------------------
__global__ __launch_bounds__(512) void scan2_kernel(int* __restrict__ bsum) {
    __shared__ int s[512];
    const int t = threadIdx.x;
    int v = (t < NBLK) ? bsum[t] : 0;
    s[t] = v;
    __syncthreads();
    #pragma unroll
    for (int off = 1; off < 512; off <<= 1) {
        int u = (t >= off) ? s[t - off] : 0;
        __syncthreads();
        s[t] += u;
        __syncthreads();
    }
    if (t < NBLK) bsum[t] = s[t] - v;
}

// ---------------------------------------------------------------------------
// CSR step 2c: add block offsets; init cursor; seed bucket cursors; close.
// ---------------------------------------------------------------------------
__global__ __launch_bounds__(256) void scan3_kernel(int* __restrict__ rowptr,
                                                    int* __restrict__ cursor,
                                                    const int* __restrict__ bsum,
                                                    int* __restrict__ bcur) {
    const int i = blockIdx.x * 256 + threadIdx.x;
    if (i < N_NODES) {
        int v = rowptr[i] + bsum[blockIdx.x];
        rowptr[i] = v;
        cursor[i] = v;
        if ((i & ((1 << BSHIFT) - 1)) == 0) bcur[i >> BSHIFT] = v;
    }
    if (i == 0) rowptr[N_NODES] = N_EDGES;
}

// ---------------------------------------------------------------------------
// R10 pass A: scatter edges into 98 row-buckets (row >> 10).
// LDS-staged: per-block bucket histogram -> one global atomicAdd per bucket
// reserves a contiguous per-(block,bucket) range (~336B avg) -> line-local
// writes. Record: x = (lrow<<17)|col, y = f32 weight.
// ---------------------------------------------------------------------------
__global__ __launch_bounds__(256) void bucket_kernel(const int* __restrict__ row,
                                                     const int* __restrict__ col,
                                                     const float* __restrict__ ew,
                                                     int* __restrict__ bcur,
                                                     int2* __restrict__ bucketed) {
    __shared__ int lcnt[NBUCK];
    __shared__ int lbase[NBUCK];
    const int t = threadIdx.x;
    for (int b = t; b < NBUCK; b += 256) lcnt[b] = 0;
    __syncthreads();

    const int e0 = blockIdx.x * CHUNK;
    int bk[16];
    int val[16];
    float w[16];
    #pragma unroll
    for (int i = 0; i < 16; i++) {
        int e = e0 + i * 256 + t;
        if (e < N_EDGES) {
            int r = row[e];
            int c = col[e];
            w[i] = ew[e];
            bk[i] = r >> BSHIFT;
            val[i] = ((r & ((1 << BSHIFT) - 1)) << 17) | c;
            atomicAdd(&lcnt[bk[i]], 1);
        } else {
            bk[i] = -1;
        }
    }
    __syncthreads();

    for (int b = t; b < NBUCK; b += 256) {
        lbase[b] = atomicAdd(&bcur[b], lcnt[b]);
        lcnt[b] = 0;   // reuse as rank counter
    }
    __syncthreads();

    #pragma unroll
    for (int i = 0; i < 16; i++) {
        if (bk[i] >= 0) {
            int pos = lbase[bk[i]] + atomicAdd(&lcnt[bk[i]], 1);
            bucketed[pos] = make_int2(val[i], __float_as_int(w[i]));
        }
    }
}

// ---------------------------------------------------------------------------
// R10 pass B: per-row scatter, now reading bucket-grouped records so each
// block's writes land in a ~130KB L2-resident bucket region. blockIdx&7
// selects a contiguous 200000-edge span so each region stays on one XCD's L2
// (perf heuristic only; correctness independent of dispatch mapping).
// ---------------------------------------------------------------------------
__global__ __launch_bounds__(256) void place_kernel(const int* __restrict__ rowptr,
                                                    const int2* __restrict__ bucketed,
                                                    int* __restrict__ cursor,
                                                    int2* __restrict__ sorted) {
    __shared__ int bb[NBUCK + 1];
    for (int b = threadIdx.x; b <= NBUCK; b += 256) {
        int rlim = (b << BSHIFT);
        bb[b] = rowptr[rlim < N_NODES ? rlim : N_NODES];
    }
    __syncthreads();

    const int x = blockIdx.x & 7;
    const int j = blockIdx.x >> 3;
    const int le = j * 256 + threadIdx.x;
    if (le >= EPX) return;
    const int e = x * EPX + le;

    // locate bucket: bb[lo] <= e < bb[lo+1]
    int lo = 0, hi = NBUCK;
    while (hi - lo > 1) {
        int mid = (lo + hi) >> 1;
        if (e >= bb[mid]) lo = mid; else hi = mid;
    }

    int2 rec = bucketed[e];
    int r = (lo << BSHIFT) + (rec.x >> 17);
    int pos = atomicAdd(&cursor[r], 1);
    sorted[pos] = make_int2(rec.x & 0x1FFFF, rec.y);
}

// ---------------------------------------------------------------------------
// Gather-reduce: agg[n][f] = sum_{e in row n} w_e * support[col_e][f].
// One wave per node (lane = feature), bf16 support, f32 accumulate.
// BN stats fused: block LDS reduce -> 128 atomics per block.
// ---------------------------------------------------------------------------
__global__ __launch_bounds__(256) void gather_kernel(const int* __restrict__ rowptr,
                                                     const int2* __restrict__ sorted,
                                                     const unsigned short* __restrict__ support,
                                                     float* __restrict__ agg,
                                                     float* __restrict__ sums) {
    const int f = threadIdx.x & 63;
    const int wv = threadIdx.x >> 6;
    const int wid = blockIdx.x * 4 + wv;
    const int nw = gridDim.x * 4;
    float s = 0.f, s2 = 0.f;

    for (int n = wid; n < N_NODES; n += nw) {
        const int jb = __builtin_amdgcn_readfirstlane(rowptr[n]);
        const int je = __builtin_amdgcn_readfirstlane(rowptr[n + 1]);
        float acc = 0.f;
        int j = jb;
        for (; j + 4 <= je; j += 4) {
            int2 a0 = sorted[j + 0];
            int2 a1 = sorted[j + 1];
            int2 a2 = sorted[j + 2];
            int2 a3 = sorted[j + 3];
            int c0 = __builtin_amdgcn_readfirstlane(a0.x);
            int c1 = __builtin_amdgcn_readfirstlane(a1.x);
            int c2 = __builtin_amdgcn_readfirstlane(a2.x);
            int c3 = __builtin_amdgcn_readfirstlane(a3.x);
            float w0 = __uint_as_float(__builtin_amdgcn_readfirstlane(a0.y));
            float w1 = __uint_as_float(__builtin_amdgcn_readfirstlane(a1.y));
            float w2 = __uint_as_float(__builtin_amdgcn_readfirstlane(a2.y));
            float w3 = __uint_as_float(__builtin_amdgcn_readfirstlane(a3.y));
            float v0 = bf2f(support[c0 * NHID + f]);
            float v1 = bf2f(support[c1 * NHID + f]);
            float v2 = bf2f(support[c2 * NHID + f]);
            float v3 = bf2f(support[c3 * NHID + f]);
            acc = fmaf(w0, v0, acc);
            acc = fmaf(w1, v1, acc);
            acc = fmaf(w2, v2, acc);
            acc = fmaf(w3, v3, acc);
        }
        for (; j < je; ++j) {
            int2 a = sorted[j];
            int c = __builtin_amdgcn_readfirstlane(a.x);
            float wgt = __uint_as_float(__builtin_amdgcn_readfirstlane(a.y));
            acc = fmaf(wgt, bf2f(support[c * NHID + f]), acc);
        }
        agg[(size_t)n * NHID + f] = acc;
        s += acc;
        s2 = fmaf(acc, acc, s2);
    }

    __shared__ float red[2][4][64];
    red[0][wv][f] = s;
    red[1][wv][f] = s2;
    __syncthreads();
    if (threadIdx.x < 64) {
        atomicAdd(&sums[f], red[0][0][f] + red[0][1][f] + red[0][2][f] + red[0][3][f]);
    } else if (threadIdx.x < 128) {
        atomicAdd(&sums[64 + f], red[1][0][f] + red[1][1][f] + red[1][2][f] + red[1][3][f]);
    }
}

// ---------------------------------------------------------------------------
// Finalize: scale = gamma*rsqrt(var+eps); shift = beta - mean*scale.
// (reference's +b cancels via BN mean subtraction; b is zeros anyway)
// ---------------------------------------------------------------------------
__global__ __launch_bounds__(64) void finalize_kernel(const float* __restrict__ sums,
                                                      const float* __restrict__ gamma,
                                                      const float* __restrict__ beta,
                                                      float* __restrict__ scaleshift) {
    const int f = threadIdx.x;
    const float inv_n = 1.0f / (float)N_NODES;
    float mean = sums[f] * inv_n;
    float var = sums[64 + f] * inv_n - mean * mean;
    float sc = gamma[f] * rsqrtf(var + 1e-5f);
    scaleshift[f] = sc;
    scaleshift[64 + f] = beta[f] - mean * sc;
}

// ---------------------------------------------------------------------------
// Threefry-2x32, 20 rounds, key=(0,42). Hand-verified vs JAX test vector.
// ---------------------------------------------------------------------------
__device__ __forceinline__ uint32_t rotl32(uint32_t x, int d) {
    return (x << d) | (x >> (32 - d));
}

__device__ __forceinline__ void threefry2x32_0_42(uint32_t x0, uint32_t x1,
                                                  uint32_t& o0, uint32_t& o1) {
    const uint32_t k0 = 0u, k1 = 42u;
    const uint32_t k2 = k0 ^ k1 ^ 0x1BD11BDAu;
    x0 += k0; x1 += k1;
    x0 += x1; x1 = rotl32(x1, 13) ^ x0;
    x0 += x1; x1 = rotl32(x1, 15) ^ x0;
    x0 += x1; x1 = rotl32(x1, 26) ^ x0;
    x0 += x1; x1 = rotl32(x1, 6)  ^ x0;
    x0 += k1; x1 += k2 + 1u;
    x0 += x1; x1 = rotl32(x1, 17) ^ x0;
    x0 += x1; x1 = rotl32(x1, 29) ^ x0;
    x0 += x1; x1 = rotl32(x1, 16) ^ x0;
    x0 += x1; x1 = rotl32(x1, 24) ^ x0;
    x0 += k2; x1 += k0 + 2u;
    x0 += x1; x1 = rotl32(x1, 13) ^ x0;
    x0 += x1; x1 = rotl32(x1, 15) ^ x0;
    x0 += x1; x1 = rotl32(x1, 26) ^ x0;
    x0 += x1; x1 = rotl32(x1, 6)  ^ x0;
    x0 += k0; x1 += k1 + 3u;
    x0 += x1; x1 = rotl32(x1, 17) ^ x0;
    x0 += x1; x1 = rotl32(x1, 29) ^ x0;
    x0 += x1; x1 = rotl32(x1, 16) ^ x0;
    x0 += x1; x1 = rotl32(x1, 24) ^ x0;
    x0 += k1; x1 += k2 + 4u;
    x0 += x1; x1 = rotl32(x1, 13) ^ x0;
    x0 += x1; x1 = rotl32(x1, 15) ^ x0;
    x0 += x1; x1 = rotl32(x1, 26) ^ x0;
    x0 += x1; x1 = rotl32(x1, 6)  ^ x0;
    x0 += k2; x1 += k0 + 5u;
    o0 = x0; o1 = x1;
}

// ---------------------------------------------------------------------------
// Apply: BN affine + ReLU + dropout; f32 out (overwrites dead support).
// ---------------------------------------------------------------------------
__global__ __launch_bounds__(256) void apply_kernel(const float* __restrict__ agg,
                                                    const float* __restrict__ scaleshift,
                                                    float* __restrict__ out) {
    const int i = blockIdx.x * 256 + threadIdx.x;
    if (i >= N_ELEMS) return;
    const int f = i & 63;
    const float sc = scaleshift[f];
    const float sh = scaleshift[64 + f];

    uint32_t o0, o1;
    threefry2x32_0_42(0u, (uint32_t)i, o0, o1);
    uint32_t bits = o0 ^ o1;
    float u = __uint_as_float((bits >> 9) | 0x3F800000u) - 1.0f;

    float v = fmaxf(fmaf(agg[i], sc, sh), 0.0f);
    out[i] = (u < 0.7f) ? v * (1.0f / 0.7f) : 0.0f;
}

// ---------------------------------------------------------------------------
extern "C" void kernel_launch(void* const* d_in, const int* in_sizes, int n_in,
                              void* d_out, int out_size, void* d_ws, size_t ws_size,
                              hipStream_t stream) {
    const float* x     = (const float*)d_in[0];
    const int*   row   = (const int*)d_in[1];
    const int*   col   = (const int*)d_in[2];
    const float* ew    = (const float*)d_in[3];
    const float* W     = (const float*)d_in[4];
    const float* gamma = (const float*)d_in[6];
    const float* beta  = (const float*)d_in[7];
    float* out = (float*)d_out;

    float* sums       = (float*)d_ws;                      // 128
    float* scaleshift = sums + 128;                        // 128
    int*   cnt        = (int*)(scaleshift + 128);          // 100000
    int*   rowptr     = cnt + N_NODES;                     // 100002
    int*   cursor     = rowptr + (N_NODES + 2);            // 100000
    int*   bsum       = cursor + N_NODES;                  // 512
    int*   bcur       = bsum + 512;                        // 128 (98 used)
    unsigned short* wt = (unsigned short*)(bcur + 128);    // 16384
    float* agg        = (float*)(wt + 16384);              // 6.4M f32
    int2*  sorted     = (int2*)(agg + (size_t)N_ELEMS);    // 1.6M int2
    unsigned short* support = (unsigned short*)out;        // 6.4M bf16, in d_out
    int2*  bucketed   = (int2*)agg;                        // aliases agg (dead)

    hipMemsetAsync(d_ws, 0, (size_t)(128 + 128 + N_NODES) * sizeof(float), stream);

    wtprep_kernel<<<64, 256, 0, stream>>>(W, wt);
    gemm_kernel<<<(N_NODES + 63) / 64, 256, 0, stream>>>(x, wt, support);

    const int epb = (N_EDGES + 255) / 256;  // 6250 blocks, 1 thread/edge
    hist_kernel<<<epb, 256, 0, stream>>>(row, cnt);
    scan1_kernel<<<NBLK, 256, 0, stream>>>(cnt, rowptr, bsum);
    scan2_kernel<<<1, 512, 0, stream>>>(bsum);
    scan3_kernel<<<NBLK, 256, 0, stream>>>(rowptr, cursor, bsum, bcur);

    bucket_kernel<<<NBBLK, 256, 0, stream>>>(row, col, ew, bcur, bucketed);
    place_kernel<<<8 * PBLK, 256, 0, stream>>>(rowptr, bucketed, cursor, sorted);

    gather_kernel<<<2048, 256, 0, stream>>>(rowptr, sorted, support, agg, sums);

    finalize_kernel<<<1, 64, 0, stream>>>(sums, gamma, beta, scaleshift);
    apply_kernel<<<(N_ELEMS + 255) / 256, 256, 0, stream>>>(agg, scaleshift, out);
}

// Round 2
// 353.364 us; speedup vs baseline: 1.3685x; 1.3685x over previous
//
#include <hip/hip_runtime.h>
#include <stdint.h>

#define N_NODES 100000
#define N_EDGES 1600000
#define NFEAT 256
#define NHID 64
#define N_ELEMS (N_NODES * NHID)   // 6,400,000

// R11: row-buckets of 128 rows; per-bucket LDS counting sort.
#define BSHIFT 7
#define NBUCK 782                  // ceil(100000/128)
#define CHUNK 4096                 // edges per bhist/bucket block
#define NBBLK ((N_EDGES + CHUNK - 1) / CHUNK)   // 391
#define CAP 2560                   // stage capacity; mean 2048, sigma ~45 -> +11s

// Config (validated R6/R7): inputs f32, output f32, dropout = JAX partitionable
// threefry (key=(0,42), counter (0,i), bits = o0^o1).
//
// R10 post-mortem: place_kernel WRITE 55MB for 12.8MB output (4.3x line amp)
//   at 650GB/s + 1.6M value-returning global atomics = 96us. Per-record global
//   scatter can't fill lines reliably.
// R11: buckets shrunk to 128 rows (16KB records). place_kernel = per-bucket
//   LDS counting sort: load bucket -> LDS hist[128] -> scan -> rank into 2nd
//   LDS stage -> stream out coalesced full lines. No global atomics.
//   Local hist + bucket-base scan also yield rowptr -> hist/scan1/2/3 deleted,
//   replaced by bhist (LDS-aggregated bucket histogram) + bscan (1 block).
//   nrec>CAP fallback: direct ranked scatter (correct, ~never taken).
//
// ws layout:
//   sums[128] f32 | hb[1024] i32 | scaleshift[128] f32 | bbase[1024] i32
//   | bcur[1024] i32 | rowptr[100004] i32 | wt[16384] ushort
//   | agg[6.4M] f32 | sorted[1.6M] int2
// support[6.4M] bf16 staged in d_out (dead before apply overwrites).
// bucketed[1.6M] int2 aliases agg (dead until gather writes agg).

typedef __attribute__((ext_vector_type(8))) short bf16x8;
typedef __attribute__((ext_vector_type(4))) float f32x4;

__device__ __forceinline__ unsigned short f2bf(float f) {
    uint32_t u = __float_as_uint(f);
    u += 0x7FFFu + ((u >> 16) & 1u);   // RNE
    return (unsigned short)(u >> 16);
}
__device__ __forceinline__ float bf2f(unsigned short u) {
    return __uint_as_float(((uint32_t)u) << 16);
}

// ---------------------------------------------------------------------------
// W^T prep: wt[n][k] = bf16(W[k][n])
// ---------------------------------------------------------------------------
__global__ __launch_bounds__(256) void wtprep_kernel(const float* __restrict__ W,
                                                     unsigned short* __restrict__ wt) {
    int i = blockIdx.x * 256 + threadIdx.x;
    if (i < NFEAT * NHID) {
        int k = i >> 6, n = i & 63;
        wt[n * NFEAT + k] = f2bf(W[i]);
    }
}

// ---------------------------------------------------------------------------
// GEMM (MFMA bf16): support[N x 64] = x[N x 256] @ W[256 x 64], bf16 out.
// ---------------------------------------------------------------------------
__global__ __launch_bounds__(256) void gemm_kernel(const float* __restrict__ x,
                                                   const unsigned short* __restrict__ wt,
                                                   unsigned short* __restrict__ support) {
    __shared__ unsigned short Abf[64][264];  // row stride 528B, 16B-aligned
    __shared__ unsigned short Bt[64][264];   // Bt[n][k]
    const int t = threadIdx.x;
    const int row0 = blockIdx.x * 64;

    {
        const int r = t >> 6;
        const int c4 = t & 63;
        #pragma unroll
        for (int rr = 0; rr < 16; rr++) {
            int lr_ = rr * 4 + r;
            int gr = row0 + lr_;
            float4 v = make_float4(0.f, 0.f, 0.f, 0.f);
            if (gr < N_NODES) v = *(const float4*)&x[(size_t)gr * NFEAT + c4 * 4];
            ushort4 u;
            u.x = f2bf(v.x); u.y = f2bf(v.y); u.z = f2bf(v.z); u.w = f2bf(v.w);
            *(ushort4*)&Abf[lr_][c4 * 4] = u;
        }
    }
    {
        const int rB = t >> 5;
        const int ch = t & 31;
        #pragma unroll
        for (int rr = 0; rr < 8; rr++) {
            int n = rr * 8 + rB;
            uint4 v = *(const uint4*)&wt[n * NFEAT + ch * 8];
            *(uint4*)&Bt[n][ch * 8] = v;
        }
    }
    __syncthreads();

    const int lane = t & 63;
    const int w = t >> 6;
    const int m = lane & 15;
    const int q = lane >> 4;
    f32x4 acc0 = {0.f, 0.f, 0.f, 0.f};
    f32x4 acc1 = acc0, acc2 = acc0, acc3 = acc0;

    #pragma unroll
    for (int ks = 0; ks < NFEAT; ks += 32) {
        bf16x8 af = *(const bf16x8*)&Abf[w * 16 + m][ks + q * 8];
        bf16x8 b0 = *(const bf16x8*)&Bt[ 0 + m][ks + q * 8];
        bf16x8 b1 = *(const bf16x8*)&Bt[16 + m][ks + q * 8];
        bf16x8 b2 = *(const bf16x8*)&Bt[32 + m][ks + q * 8];
        bf16x8 b3 = *(const bf16x8*)&Bt[48 + m][ks + q * 8];
        acc0 = __builtin_amdgcn_mfma_f32_16x16x32_bf16(af, b0, acc0, 0, 0, 0);
        acc1 = __builtin_amdgcn_mfma_f32_16x16x32_bf16(af, b1, acc1, 0, 0, 0);
        acc2 = __builtin_amdgcn_mfma_f32_16x16x32_bf16(af, b2, acc2, 0, 0, 0);
        acc3 = __builtin_amdgcn_mfma_f32_16x16x32_bf16(af, b3, acc3, 0, 0, 0);
    }

    // C/D layout: row = q*4 + reg, col = nt*16 + m
    #pragma unroll
    for (int reg = 0; reg < 4; reg++) {
        int grow = row0 + w * 16 + q * 4 + reg;
        if (grow < N_NODES) {
            support[(size_t)grow * NHID +  0 + m] = f2bf(acc0[reg]);
            support[(size_t)grow * NHID + 16 + m] = f2bf(acc1[reg]);
            support[(size_t)grow * NHID + 32 + m] = f2bf(acc2[reg]);
            support[(size_t)grow * NHID + 48 + m] = f2bf(acc3[reg]);
        }
    }
}

// ---------------------------------------------------------------------------
// R11: bucket-level histogram (LDS-aggregated; 306K global atomics on 782
// counters total).
// ---------------------------------------------------------------------------
__global__ __launch_bounds__(256) void bhist_kernel(const int* __restrict__ row,
                                                    int* __restrict__ hb) {
    __shared__ int lcnt[NBUCK];
    const int t = threadIdx.x;
    for (int b = t; b < NBUCK; b += 256) lcnt[b] = 0;
    __syncthreads();
    const int e0 = blockIdx.x * CHUNK;
    #pragma unroll
    for (int i = 0; i < 16; i++) {
        int e = e0 + i * 256 + t;
        if (e < N_EDGES) atomicAdd(&lcnt[row[e] >> BSHIFT], 1);
    }
    __syncthreads();
    for (int b = t; b < NBUCK; b += 256) {
        int c = lcnt[b];
        if (c) atomicAdd(&hb[b], c);
    }
}

// ---------------------------------------------------------------------------
// R11: exclusive scan of bucket counts -> bucket bases; seed bucket cursors.
// ---------------------------------------------------------------------------
__global__ __launch_bounds__(1024) void bscan_kernel(const int* __restrict__ hb,
                                                     int* __restrict__ bbase,
                                                     int* __restrict__ bcur,
                                                     int* __restrict__ rowptr) {
    __shared__ int s[1024];
    const int t = threadIdx.x;
    int v = (t < NBUCK) ? hb[t] : 0;
    s[t] = v;
    __syncthreads();
    #pragma unroll
    for (int off = 1; off < 1024; off <<= 1) {
        int u = (t >= off) ? s[t - off] : 0;
        __syncthreads();
        s[t] += u;
        __syncthreads();
    }
    if (t < NBUCK) {
        int base = s[t] - v;
        bbase[t] = base;
        bcur[t] = base;
    }
    if (t == 0) rowptr[N_NODES] = N_EDGES;
}

// ---------------------------------------------------------------------------
// Pass A: scatter edges into 782 row-buckets (row >> 7).
// Per-block LDS histogram -> one global atomicAdd per nonempty bucket
// reserves a contiguous run. Record: x = (lrow<<17)|col, y = f32 weight.
// ---------------------------------------------------------------------------
__global__ __launch_bounds__(256) void bucket_kernel(const int* __restrict__ row,
                                                     const int* __restrict__ col,
                                                     const float* __restrict__ ew,
                                                     int* __restrict__ bcur,
                                                     int2* __restrict__ bucketed) {
    __shared__ int lcnt[NBUCK];
    __shared__ int lbase[NBUCK];
    const int t = threadIdx.x;
    for (int b = t; b < NBUCK; b += 256) lcnt[b] = 0;
    __syncthreads();

    const int e0 = blockIdx.x * CHUNK;
    int bk[16];
    int val[16];
    float w[16];
    #pragma unroll
    for (int i = 0; i < 16; i++) {
        int e = e0 + i * 256 + t;
        if (e < N_EDGES) {
            int r = row[e];
            int c = col[e];
            w[i] = ew[e];
            bk[i] = r >> BSHIFT;
            val[i] = ((r & ((1 << BSHIFT) - 1)) << 17) | c;
            atomicAdd(&lcnt[bk[i]], 1);
        } else {
            bk[i] = -1;
        }
    }
    __syncthreads();

    for (int b = t; b < NBUCK; b += 256) {
        int c = lcnt[b];
        lbase[b] = c ? atomicAdd(&bcur[b], c) : 0;
        lcnt[b] = 0;   // reuse as rank counter
    }
    __syncthreads();

    #pragma unroll
    for (int i = 0; i < 16; i++) {
        if (bk[i] >= 0) {
            int pos = lbase[bk[i]] + atomicAdd(&lcnt[bk[i]], 1);
            bucketed[pos] = make_int2(val[i], __float_as_int(w[i]));
        }
    }
}

// ---------------------------------------------------------------------------
// Pass B (R11): per-bucket LDS counting sort. One block per 128-row bucket.
// Loads the ~16KB bucket into LDS, histograms rows, scans, ranks into a
// second stage, streams out fully-coalesced. Also emits rowptr for the
// bucket's rows (bs + local exclusive offsets). No global atomics.
// Fallback for nrec>CAP: ranked direct scatter (correct, ~never taken).
// ---------------------------------------------------------------------------
__global__ __launch_bounds__(256) void place_kernel(const int* __restrict__ bbase,
                                                    const int* __restrict__ hb,
                                                    const int2* __restrict__ bucketed,
                                                    int2* __restrict__ sorted,
                                                    int* __restrict__ rowptr) {
    __shared__ int2 stage[CAP];    // 20KB
    __shared__ int2 stage2[CAP];   // 20KB
    __shared__ int hcnt[128];
    __shared__ int hs[128];
    const int t = threadIdx.x;
    const int b = blockIdx.x;
    const int bs = bbase[b];
    const int nrec = hb[b];
    const bool fit = (nrec <= CAP);

    if (t < 128) hcnt[t] = 0;
    __syncthreads();

    for (int i = t; i < nrec; i += 256) {
        int2 rec = bucketed[bs + i];
        if (fit) stage[i] = rec;
        atomicAdd(&hcnt[rec.x >> 17], 1);
    }
    __syncthreads();

    // Hillis-Steele inclusive scan over 128 counters.
    int v0 = (t < 128) ? hcnt[t] : 0;
    if (t < 128) hs[t] = v0;
    __syncthreads();
    #pragma unroll
    for (int off = 1; off < 128; off <<= 1) {
        int u = (t < 128 && t >= off) ? hs[t - off] : 0;
        __syncthreads();
        if (t < 128) hs[t] += u;
        __syncthreads();
    }
    // exclusive offset for row t; write rowptr; reset hcnt as running cursor
    if (t < 128) {
        int excl = hs[t] - v0;
        int r = (b << BSHIFT) + t;
        if (r < N_NODES) rowptr[r] = bs + excl;
        hcnt[t] = excl;
    }
    __syncthreads();

    if (fit) {
        for (int i = t; i < nrec; i += 256) {
            int2 rec = stage[i];
            int lr = rec.x >> 17;
            int pos = atomicAdd(&hcnt[lr], 1);
            stage2[pos] = make_int2(rec.x & 0x1FFFF, rec.y);
        }
        __syncthreads();
        for (int i = t; i < nrec; i += 256) {
            sorted[bs + i] = stage2[i];
        }
    } else {
        for (int i = t; i < nrec; i += 256) {
            int2 rec = bucketed[bs + i];
            int lr = rec.x >> 17;
            int pos = atomicAdd(&hcnt[lr], 1);
            sorted[bs + pos] = make_int2(rec.x & 0x1FFFF, rec.y);
        }
    }
}

// ---------------------------------------------------------------------------
// Gather-reduce: agg[n][f] = sum_{e in row n} w_e * support[col_e][f].
// One wave per node (lane = feature), bf16 support, f32 accumulate.
// BN stats fused: block LDS reduce -> 128 atomics per block.
// ---------------------------------------------------------------------------
__global__ __launch_bounds__(256) void gather_kernel(const int* __restrict__ rowptr,
                                                     const int2* __restrict__ sorted,
                                                     const unsigned short* __restrict__ support,
                                                     float* __restrict__ agg,
                                                     float* __restrict__ sums) {
    const int f = threadIdx.x & 63;
    const int wv = threadIdx.x >> 6;
    const int wid = blockIdx.x * 4 + wv;
    const int nw = gridDim.x * 4;
    float s = 0.f, s2 = 0.f;

    for (int n = wid; n < N_NODES; n += nw) {
        const int jb = __builtin_amdgcn_readfirstlane(rowptr[n]);
        const int je = __builtin_amdgcn_readfirstlane(rowptr[n + 1]);
        float acc = 0.f;
        int j = jb;
        for (; j + 4 <= je; j += 4) {
            int2 a0 = sorted[j + 0];
            int2 a1 = sorted[j + 1];
            int2 a2 = sorted[j + 2];
            int2 a3 = sorted[j + 3];
            int c0 = __builtin_amdgcn_readfirstlane(a0.x);
            int c1 = __builtin_amdgcn_readfirstlane(a1.x);
            int c2 = __builtin_amdgcn_readfirstlane(a2.x);
            int c3 = __builtin_amdgcn_readfirstlane(a3.x);
            float w0 = __uint_as_float(__builtin_amdgcn_readfirstlane(a0.y));
            float w1 = __uint_as_float(__builtin_amdgcn_readfirstlane(a1.y));
            float w2 = __uint_as_float(__builtin_amdgcn_readfirstlane(a2.y));
            float w3 = __uint_as_float(__builtin_amdgcn_readfirstlane(a3.y));
            float v0 = bf2f(support[c0 * NHID + f]);
            float v1 = bf2f(support[c1 * NHID + f]);
            float v2 = bf2f(support[c2 * NHID + f]);
            float v3 = bf2f(support[c3 * NHID + f]);
            acc = fmaf(w0, v0, acc);
            acc = fmaf(w1, v1, acc);
            acc = fmaf(w2, v2, acc);
            acc = fmaf(w3, v3, acc);
        }
        for (; j < je; ++j) {
            int2 a = sorted[j];
            int c = __builtin_amdgcn_readfirstlane(a.x);
            float wgt = __uint_as_float(__builtin_amdgcn_readfirstlane(a.y));
            acc = fmaf(wgt, bf2f(support[c * NHID + f]), acc);
        }
        agg[(size_t)n * NHID + f] = acc;
        s += acc;
        s2 = fmaf(acc, acc, s2);
    }

    __shared__ float red[2][4][64];
    red[0][wv][f] = s;
    red[1][wv][f] = s2;
    __syncthreads();
    if (threadIdx.x < 64) {
        atomicAdd(&sums[f], red[0][0][f] + red[0][1][f] + red[0][2][f] + red[0][3][f]);
    } else if (threadIdx.x < 128) {
        atomicAdd(&sums[64 + f], red[1][0][f] + red[1][1][f] + red[1][2][f] + red[1][3][f]);
    }
}

// ---------------------------------------------------------------------------
// Finalize: scale = gamma*rsqrt(var+eps); shift = beta - mean*scale.
// ---------------------------------------------------------------------------
__global__ __launch_bounds__(64) void finalize_kernel(const float* __restrict__ sums,
                                                      const float* __restrict__ gamma,
                                                      const float* __restrict__ beta,
                                                      float* __restrict__ scaleshift) {
    const int f = threadIdx.x;
    const float inv_n = 1.0f / (float)N_NODES;
    float mean = sums[f] * inv_n;
    float var = sums[64 + f] * inv_n - mean * mean;
    float sc = gamma[f] * rsqrtf(var + 1e-5f);
    scaleshift[f] = sc;
    scaleshift[64 + f] = beta[f] - mean * sc;
}

// ---------------------------------------------------------------------------
// Threefry-2x32, 20 rounds, key=(0,42). Hand-verified vs JAX test vector.
// ---------------------------------------------------------------------------
__device__ __forceinline__ uint32_t rotl32(uint32_t x, int d) {
    return (x << d) | (x >> (32 - d));
}

__device__ __forceinline__ void threefry2x32_0_42(uint32_t x0, uint32_t x1,
                                                  uint32_t& o0, uint32_t& o1) {
    const uint32_t k0 = 0u, k1 = 42u;
    const uint32_t k2 = k0 ^ k1 ^ 0x1BD11BDAu;
    x0 += k0; x1 += k1;
    x0 += x1; x1 = rotl32(x1, 13) ^ x0;
    x0 += x1; x1 = rotl32(x1, 15) ^ x0;
    x0 += x1; x1 = rotl32(x1, 26) ^ x0;
    x0 += x1; x1 = rotl32(x1, 6)  ^ x0;
    x0 += k1; x1 += k2 + 1u;
    x0 += x1; x1 = rotl32(x1, 17) ^ x0;
    x0 += x1; x1 = rotl32(x1, 29) ^ x0;
    x0 += x1; x1 = rotl32(x1, 16) ^ x0;
    x0 += x1; x1 = rotl32(x1, 24) ^ x0;
    x0 += k2; x1 += k0 + 2u;
    x0 += x1; x1 = rotl32(x1, 13) ^ x0;
    x0 += x1; x1 = rotl32(x1, 15) ^ x0;
    x0 += x1; x1 = rotl32(x1, 26) ^ x0;
    x0 += x1; x1 = rotl32(x1, 6)  ^ x0;
    x0 += k0; x1 += k1 + 3u;
    x0 += x1; x1 = rotl32(x1, 17) ^ x0;
    x0 += x1; x1 = rotl32(x1, 29) ^ x0;
    x0 += x1; x1 = rotl32(x1, 16) ^ x0;
    x0 += x1; x1 = rotl32(x1, 24) ^ x0;
    x0 += k1; x1 += k2 + 4u;
    x0 += x1; x1 = rotl32(x1, 13) ^ x0;
    x0 += x1; x1 = rotl32(x1, 15) ^ x0;
    x0 += x1; x1 = rotl32(x1, 26) ^ x0;
    x0 += x1; x1 = rotl32(x1, 6)  ^ x0;
    x0 += k2; x1 += k0 + 5u;
    o0 = x0; o1 = x1;
}

// ---------------------------------------------------------------------------
// Apply: BN affine + ReLU + dropout; f32 out (overwrites dead support).
// ---------------------------------------------------------------------------
__global__ __launch_bounds__(256) void apply_kernel(const float* __restrict__ agg,
                                                    const float* __restrict__ scaleshift,
                                                    float* __restrict__ out) {
    const int i = blockIdx.x * 256 + threadIdx.x;
    if (i >= N_ELEMS) return;
    const int f = i & 63;
    const float sc = scaleshift[f];
    const float sh = scaleshift[64 + f];

    uint32_t o0, o1;
    threefry2x32_0_42(0u, (uint32_t)i, o0, o1);
    uint32_t bits = o0 ^ o1;
    float u = __uint_as_float((bits >> 9) | 0x3F800000u) - 1.0f;

    float v = fmaxf(fmaf(agg[i], sc, sh), 0.0f);
    out[i] = (u < 0.7f) ? v * (1.0f / 0.7f) : 0.0f;
}

// ---------------------------------------------------------------------------
extern "C" void kernel_launch(void* const* d_in, const int* in_sizes, int n_in,
                              void* d_out, int out_size, void* d_ws, size_t ws_size,
                              hipStream_t stream) {
    const float* x     = (const float*)d_in[0];
    const int*   row   = (const int*)d_in[1];
    const int*   col   = (const int*)d_in[2];
    const float* ew    = (const float*)d_in[3];
    const float* W     = (const float*)d_in[4];
    const float* gamma = (const float*)d_in[6];
    const float* beta  = (const float*)d_in[7];
    float* out = (float*)d_out;

    float* sums       = (float*)d_ws;                      // 128 f32
    int*   hb         = (int*)(sums + 128);                // 1024 i32 (782 used)
    float* scaleshift = (float*)(hb + 1024);               // 128 f32
    int*   bbase      = (int*)(scaleshift + 128);          // 1024 i32
    int*   bcur       = bbase + 1024;                      // 1024 i32
    int*   rowptr     = bcur + 1024;                       // 100004 i32
    unsigned short* wt = (unsigned short*)(rowptr + 100004); // 16384 ushort
    float* agg        = (float*)(wt + 16384);              // 6.4M f32
    int2*  sorted     = (int2*)(agg + (size_t)N_ELEMS);    // 1.6M int2
    unsigned short* support = (unsigned short*)out;        // 6.4M bf16, in d_out
    int2*  bucketed   = (int2*)agg;                        // aliases agg (dead)

    // zero sums + hb (adjacent)
    hipMemsetAsync(d_ws, 0, (size_t)(128 + 1024) * 4, stream);

    wtprep_kernel<<<64, 256, 0, stream>>>(W, wt);
    gemm_kernel<<<(N_NODES + 63) / 64, 256, 0, stream>>>(x, wt, support);

    bhist_kernel<<<NBBLK, 256, 0, stream>>>(row, hb);
    bscan_kernel<<<1, 1024, 0, stream>>>(hb, bbase, bcur, rowptr);
    bucket_kernel<<<NBBLK, 256, 0, stream>>>(row, col, ew, bcur, bucketed);
    place_kernel<<<NBUCK, 256, 0, stream>>>(bbase, hb, bucketed, sorted, rowptr);

    gather_kernel<<<2048, 256, 0, stream>>>(rowptr, sorted, support, agg, sums);

    finalize_kernel<<<1, 64, 0, stream>>>(sums, gamma, beta, scaleshift);
    apply_kernel<<<(N_ELEMS + 255) / 256, 256, 0, stream>>>(agg, scaleshift, out);
}

// Round 3
// 345.492 us; speedup vs baseline: 1.3997x; 1.0228x over previous
//
#include <hip/hip_runtime.h>
#include <stdint.h>

#define N_NODES 100000
#define N_EDGES 1600000
#define NFEAT 256
#define NHID 64
#define N_ELEMS (N_NODES * NHID)   // 6,400,000

// R11: row-buckets of 128 rows; per-bucket LDS counting sort.
#define BSHIFT 7
#define NBUCK 782                  // ceil(100000/128)
#define CHUNK 4096                 // edges per bhist/bucket block
#define NBBLK ((N_EDGES + CHUNK - 1) / CHUNK)   // 391
#define CAP 2560                   // stage capacity; mean 2048, sigma ~45 -> +11s

// R12: gather made latency-lean: wave = 13 contiguous nodes, lane-parallel
// rowptr load (1 coalesced load / 13 nodes), lane-parallel sorted-run load
// (1 coalesced load / node), per-edge col/weight via readlane (register ops,
// no memory round-trip) -> support gathers issue back-to-back.
#define NPW 13                     // nodes per wave
#define GWAVES ((N_NODES + NPW - 1) / NPW)      // 7693
#define GBLK ((GWAVES + 3) / 4)                 // 1924

// Config (validated R6/R7): inputs f32, output f32, dropout = JAX partitionable
// threefry (key=(0,42), counter (0,i), bits = o0^o1).
//
// R10 post-mortem: per-record global scatter can't fill lines -> R11 bucketed
//   LDS counting sort (place 96us -> small; hist/scans deleted). 483 -> 353us.
// R12 post-mortem target: gather 87us @ 1.4TB/s, VALUBusy 16% = latency-bound
//   on serial uniform sorted/rowptr loads + readfirstlane chains. FETCH 92MB
//   is ~structural floor (8 XCDs x 12.8MB support, random cols).
//
// ws layout:
//   sums[128] f32 | hb[1024] i32 | scaleshift[128] f32 | bbase[1024] i32
//   | bcur[1024] i32 | rowptr[100004] i32 | wt[16384] ushort
//   | agg[6.4M] f32 | sorted[1.6M] int2
// support[6.4M] bf16 staged in d_out (dead before apply overwrites).
// bucketed[1.6M] int2 aliases agg (dead until gather writes agg).

typedef __attribute__((ext_vector_type(8))) short bf16x8;
typedef __attribute__((ext_vector_type(4))) float f32x4;

__device__ __forceinline__ unsigned short f2bf(float f) {
    uint32_t u = __float_as_uint(f);
    u += 0x7FFFu + ((u >> 16) & 1u);   // RNE
    return (unsigned short)(u >> 16);
}
__device__ __forceinline__ float bf2f(unsigned short u) {
    return __uint_as_float(((uint32_t)u) << 16);
}

// ---------------------------------------------------------------------------
// W^T prep: wt[n][k] = bf16(W[k][n])
// ---------------------------------------------------------------------------
__global__ __launch_bounds__(256) void wtprep_kernel(const float* __restrict__ W,
                                                     unsigned short* __restrict__ wt) {
    int i = blockIdx.x * 256 + threadIdx.x;
    if (i < NFEAT * NHID) {
        int k = i >> 6, n = i & 63;
        wt[n * NFEAT + k] = f2bf(W[i]);
    }
}

// ---------------------------------------------------------------------------
// GEMM (MFMA bf16): support[N x 64] = x[N x 256] @ W[256 x 64], bf16 out.
// ---------------------------------------------------------------------------
__global__ __launch_bounds__(256) void gemm_kernel(const float* __restrict__ x,
                                                   const unsigned short* __restrict__ wt,
                                                   unsigned short* __restrict__ support) {
    __shared__ unsigned short Abf[64][264];  // row stride 528B, 16B-aligned
    __shared__ unsigned short Bt[64][264];   // Bt[n][k]
    const int t = threadIdx.x;
    const int row0 = blockIdx.x * 64;

    {
        const int r = t >> 6;
        const int c4 = t & 63;
        #pragma unroll
        for (int rr = 0; rr < 16; rr++) {
            int lr_ = rr * 4 + r;
            int gr = row0 + lr_;
            float4 v = make_float4(0.f, 0.f, 0.f, 0.f);
            if (gr < N_NODES) v = *(const float4*)&x[(size_t)gr * NFEAT + c4 * 4];
            ushort4 u;
            u.x = f2bf(v.x); u.y = f2bf(v.y); u.z = f2bf(v.z); u.w = f2bf(v.w);
            *(ushort4*)&Abf[lr_][c4 * 4] = u;
        }
    }
    {
        const int rB = t >> 5;
        const int ch = t & 31;
        #pragma unroll
        for (int rr = 0; rr < 8; rr++) {
            int n = rr * 8 + rB;
            uint4 v = *(const uint4*)&wt[n * NFEAT + ch * 8];
            *(uint4*)&Bt[n][ch * 8] = v;
        }
    }
    __syncthreads();

    const int lane = t & 63;
    const int w = t >> 6;
    const int m = lane & 15;
    const int q = lane >> 4;
    f32x4 acc0 = {0.f, 0.f, 0.f, 0.f};
    f32x4 acc1 = acc0, acc2 = acc0, acc3 = acc0;

    #pragma unroll
    for (int ks = 0; ks < NFEAT; ks += 32) {
        bf16x8 af = *(const bf16x8*)&Abf[w * 16 + m][ks + q * 8];
        bf16x8 b0 = *(const bf16x8*)&Bt[ 0 + m][ks + q * 8];
        bf16x8 b1 = *(const bf16x8*)&Bt[16 + m][ks + q * 8];
        bf16x8 b2 = *(const bf16x8*)&Bt[32 + m][ks + q * 8];
        bf16x8 b3 = *(const bf16x8*)&Bt[48 + m][ks + q * 8];
        acc0 = __builtin_amdgcn_mfma_f32_16x16x32_bf16(af, b0, acc0, 0, 0, 0);
        acc1 = __builtin_amdgcn_mfma_f32_16x16x32_bf16(af, b1, acc1, 0, 0, 0);
        acc2 = __builtin_amdgcn_mfma_f32_16x16x32_bf16(af, b2, acc2, 0, 0, 0);
        acc3 = __builtin_amdgcn_mfma_f32_16x16x32_bf16(af, b3, acc3, 0, 0, 0);
    }

    // C/D layout: row = q*4 + reg, col = nt*16 + m
    #pragma unroll
    for (int reg = 0; reg < 4; reg++) {
        int grow = row0 + w * 16 + q * 4 + reg;
        if (grow < N_NODES) {
            support[(size_t)grow * NHID +  0 + m] = f2bf(acc0[reg]);
            support[(size_t)grow * NHID + 16 + m] = f2bf(acc1[reg]);
            support[(size_t)grow * NHID + 32 + m] = f2bf(acc2[reg]);
            support[(size_t)grow * NHID + 48 + m] = f2bf(acc3[reg]);
        }
    }
}

// ---------------------------------------------------------------------------
// Bucket-level histogram (LDS-aggregated).
// ---------------------------------------------------------------------------
__global__ __launch_bounds__(256) void bhist_kernel(const int* __restrict__ row,
                                                    int* __restrict__ hb) {
    __shared__ int lcnt[NBUCK];
    const int t = threadIdx.x;
    for (int b = t; b < NBUCK; b += 256) lcnt[b] = 0;
    __syncthreads();
    const int e0 = blockIdx.x * CHUNK;
    #pragma unroll
    for (int i = 0; i < 16; i++) {
        int e = e0 + i * 256 + t;
        if (e < N_EDGES) atomicAdd(&lcnt[row[e] >> BSHIFT], 1);
    }
    __syncthreads();
    for (int b = t; b < NBUCK; b += 256) {
        int c = lcnt[b];
        if (c) atomicAdd(&hb[b], c);
    }
}

// ---------------------------------------------------------------------------
// Exclusive scan of bucket counts -> bucket bases; seed bucket cursors.
// ---------------------------------------------------------------------------
__global__ __launch_bounds__(1024) void bscan_kernel(const int* __restrict__ hb,
                                                     int* __restrict__ bbase,
                                                     int* __restrict__ bcur,
                                                     int* __restrict__ rowptr) {
    __shared__ int s[1024];
    const int t = threadIdx.x;
    int v = (t < NBUCK) ? hb[t] : 0;
    s[t] = v;
    __syncthreads();
    #pragma unroll
    for (int off = 1; off < 1024; off <<= 1) {
        int u = (t >= off) ? s[t - off] : 0;
        __syncthreads();
        s[t] += u;
        __syncthreads();
    }
    if (t < NBUCK) {
        int base = s[t] - v;
        bbase[t] = base;
        bcur[t] = base;
    }
    if (t == 0) rowptr[N_NODES] = N_EDGES;
}

// ---------------------------------------------------------------------------
// Pass A: scatter edges into 782 row-buckets (row >> 7).
// ---------------------------------------------------------------------------
__global__ __launch_bounds__(256) void bucket_kernel(const int* __restrict__ row,
                                                     const int* __restrict__ col,
                                                     const float* __restrict__ ew,
                                                     int* __restrict__ bcur,
                                                     int2* __restrict__ bucketed) {
    __shared__ int lcnt[NBUCK];
    __shared__ int lbase[NBUCK];
    const int t = threadIdx.x;
    for (int b = t; b < NBUCK; b += 256) lcnt[b] = 0;
    __syncthreads();

    const int e0 = blockIdx.x * CHUNK;
    int bk[16];
    int val[16];
    float w[16];
    #pragma unroll
    for (int i = 0; i < 16; i++) {
        int e = e0 + i * 256 + t;
        if (e < N_EDGES) {
            int r = row[e];
            int c = col[e];
            w[i] = ew[e];
            bk[i] = r >> BSHIFT;
            val[i] = ((r & ((1 << BSHIFT) - 1)) << 17) | c;
            atomicAdd(&lcnt[bk[i]], 1);
        } else {
            bk[i] = -1;
        }
    }
    __syncthreads();

    for (int b = t; b < NBUCK; b += 256) {
        int c = lcnt[b];
        lbase[b] = c ? atomicAdd(&bcur[b], c) : 0;
        lcnt[b] = 0;   // reuse as rank counter
    }
    __syncthreads();

    #pragma unroll
    for (int i = 0; i < 16; i++) {
        if (bk[i] >= 0) {
            int pos = lbase[bk[i]] + atomicAdd(&lcnt[bk[i]], 1);
            bucketed[pos] = make_int2(val[i], __float_as_int(w[i]));
        }
    }
}

// ---------------------------------------------------------------------------
// Pass B: per-bucket LDS counting sort; also emits rowptr. No global atomics.
// ---------------------------------------------------------------------------
__global__ __launch_bounds__(256) void place_kernel(const int* __restrict__ bbase,
                                                    const int* __restrict__ hb,
                                                    const int2* __restrict__ bucketed,
                                                    int2* __restrict__ sorted,
                                                    int* __restrict__ rowptr) {
    __shared__ int2 stage[CAP];    // 20KB
    __shared__ int2 stage2[CAP];   // 20KB
    __shared__ int hcnt[128];
    __shared__ int hs[128];
    const int t = threadIdx.x;
    const int b = blockIdx.x;
    const int bs = bbase[b];
    const int nrec = hb[b];
    const bool fit = (nrec <= CAP);

    if (t < 128) hcnt[t] = 0;
    __syncthreads();

    for (int i = t; i < nrec; i += 256) {
        int2 rec = bucketed[bs + i];
        if (fit) stage[i] = rec;
        atomicAdd(&hcnt[rec.x >> 17], 1);
    }
    __syncthreads();

    // Hillis-Steele inclusive scan over 128 counters.
    int v0 = (t < 128) ? hcnt[t] : 0;
    if (t < 128) hs[t] = v0;
    __syncthreads();
    #pragma unroll
    for (int off = 1; off < 128; off <<= 1) {
        int u = (t < 128 && t >= off) ? hs[t - off] : 0;
        __syncthreads();
        if (t < 128) hs[t] += u;
        __syncthreads();
    }
    if (t < 128) {
        int excl = hs[t] - v0;
        int r = (b << BSHIFT) + t;
        if (r < N_NODES) rowptr[r] = bs + excl;
        hcnt[t] = excl;
    }
    __syncthreads();

    if (fit) {
        for (int i = t; i < nrec; i += 256) {
            int2 rec = stage[i];
            int lr = rec.x >> 17;
            int pos = atomicAdd(&hcnt[lr], 1);
            stage2[pos] = make_int2(rec.x & 0x1FFFF, rec.y);
        }
        __syncthreads();
        for (int i = t; i < nrec; i += 256) {
            sorted[bs + i] = stage2[i];
        }
    } else {
        for (int i = t; i < nrec; i += 256) {
            int2 rec = bucketed[bs + i];
            int lr = rec.x >> 17;
            int pos = atomicAdd(&hcnt[lr], 1);
            sorted[bs + pos] = make_int2(rec.x & 0x1FFFF, rec.y);
        }
    }
}

// ---------------------------------------------------------------------------
// Gather-reduce (R12): wave = NPW contiguous nodes, lane = feature.
//   - rowptr for the whole span: ONE coalesced lane-parallel load.
//   - sorted run per node: ONE coalesced lane-parallel load (lane e = edge e).
//   - per-edge col/weight via readlane (no memory round-trip).
// BN stats fused: block LDS reduce -> 128 atomics per block.
// ---------------------------------------------------------------------------
__global__ __launch_bounds__(256) void gather_kernel(const int* __restrict__ rowptr,
                                                     const int2* __restrict__ sorted,
                                                     const unsigned short* __restrict__ support,
                                                     float* __restrict__ agg,
                                                     float* __restrict__ sums) {
    const int f = threadIdx.x & 63;
    const int wv = threadIdx.x >> 6;
    const int wid = blockIdx.x * 4 + wv;
    const int n0 = wid * NPW;
    float s = 0.f, s2 = 0.f;

    if (n0 < N_NODES) {
        const int n1 = (n0 + NPW < N_NODES) ? n0 + NPW : N_NODES;
        const int nn = n1 - n0;
        int rp = 0;
        if (f <= nn) rp = rowptr[n0 + f];   // lanes 0..nn hold span rowptr

        for (int i = 0; i < nn; i++) {
            const int jb = __builtin_amdgcn_readlane(rp, i);
            const int je = __builtin_amdgcn_readlane(rp, i + 1);
            float acc0 = 0.f, acc1 = 0.f;

            for (int base = jb; base < je; base += 64) {
                const int cnt = (je - base < 64) ? je - base : 64;
                int2 rec = make_int2(0, 0);
                if (f < cnt) rec = sorted[base + f];
                int e = 0;
                for (; e + 8 <= cnt; e += 8) {
                    int c0 = __builtin_amdgcn_readlane(rec.x, e + 0);
                    int c1 = __builtin_amdgcn_readlane(rec.x, e + 1);
                    int c2 = __builtin_amdgcn_readlane(rec.x, e + 2);
                    int c3 = __builtin_amdgcn_readlane(rec.x, e + 3);
                    int c4 = __builtin_amdgcn_readlane(rec.x, e + 4);
                    int c5 = __builtin_amdgcn_readlane(rec.x, e + 5);
                    int c6 = __builtin_amdgcn_readlane(rec.x, e + 6);
                    int c7 = __builtin_amdgcn_readlane(rec.x, e + 7);
                    float w0 = __uint_as_float(__builtin_amdgcn_readlane(rec.y, e + 0));
                    float w1 = __uint_as_float(__builtin_amdgcn_readlane(rec.y, e + 1));
                    float w2 = __uint_as_float(__builtin_amdgcn_readlane(rec.y, e + 2));
                    float w3 = __uint_as_float(__builtin_amdgcn_readlane(rec.y, e + 3));
                    float w4 = __uint_as_float(__builtin_amdgcn_readlane(rec.y, e + 4));
                    float w5 = __uint_as_float(__builtin_amdgcn_readlane(rec.y, e + 5));
                    float w6 = __uint_as_float(__builtin_amdgcn_readlane(rec.y, e + 6));
                    float w7 = __uint_as_float(__builtin_amdgcn_readlane(rec.y, e + 7));
                    float v0 = bf2f(support[c0 * NHID + f]);
                    float v1 = bf2f(support[c1 * NHID + f]);
                    float v2 = bf2f(support[c2 * NHID + f]);
                    float v3 = bf2f(support[c3 * NHID + f]);
                    float v4 = bf2f(support[c4 * NHID + f]);
                    float v5 = bf2f(support[c5 * NHID + f]);
                    float v6 = bf2f(support[c6 * NHID + f]);
                    float v7 = bf2f(support[c7 * NHID + f]);
                    acc0 = fmaf(w0, v0, acc0);
                    acc1 = fmaf(w1, v1, acc1);
                    acc0 = fmaf(w2, v2, acc0);
                    acc1 = fmaf(w3, v3, acc1);
                    acc0 = fmaf(w4, v4, acc0);
                    acc1 = fmaf(w5, v5, acc1);
                    acc0 = fmaf(w6, v6, acc0);
                    acc1 = fmaf(w7, v7, acc1);
                }
                for (; e + 4 <= cnt; e += 4) {
                    int c0 = __builtin_amdgcn_readlane(rec.x, e + 0);
                    int c1 = __builtin_amdgcn_readlane(rec.x, e + 1);
                    int c2 = __builtin_amdgcn_readlane(rec.x, e + 2);
                    int c3 = __builtin_amdgcn_readlane(rec.x, e + 3);
                    float w0 = __uint_as_float(__builtin_amdgcn_readlane(rec.y, e + 0));
                    float w1 = __uint_as_float(__builtin_amdgcn_readlane(rec.y, e + 1));
                    float w2 = __uint_as_float(__builtin_amdgcn_readlane(rec.y, e + 2));
                    float w3 = __uint_as_float(__builtin_amdgcn_readlane(rec.y, e + 3));
                    float v0 = bf2f(support[c0 * NHID + f]);
                    float v1 = bf2f(support[c1 * NHID + f]);
                    float v2 = bf2f(support[c2 * NHID + f]);
                    float v3 = bf2f(support[c3 * NHID + f]);
                    acc0 = fmaf(w0, v0, acc0);
                    acc1 = fmaf(w1, v1, acc1);
                    acc0 = fmaf(w2, v2, acc0);
                    acc1 = fmaf(w3, v3, acc1);
                }
                for (; e < cnt; ++e) {
                    int c = __builtin_amdgcn_readlane(rec.x, e);
                    float wgt = __uint_as_float(__builtin_amdgcn_readlane(rec.y, e));
                    acc0 = fmaf(wgt, bf2f(support[c * NHID + f]), acc0);
                }
            }
            float acc = acc0 + acc1;
            agg[(size_t)(n0 + i) * NHID + f] = acc;
            s += acc;
            s2 = fmaf(acc, acc, s2);
        }
    }

    __shared__ float red[2][4][64];
    red[0][wv][f] = s;
    red[1][wv][f] = s2;
    __syncthreads();
    if (threadIdx.x < 64) {
        atomicAdd(&sums[f], red[0][0][f] + red[0][1][f] + red[0][2][f] + red[0][3][f]);
    } else if (threadIdx.x < 128) {
        atomicAdd(&sums[64 + f], red[1][0][f] + red[1][1][f] + red[1][2][f] + red[1][3][f]);
    }
}

// ---------------------------------------------------------------------------
// Finalize: scale = gamma*rsqrt(var+eps); shift = beta - mean*scale.
// ---------------------------------------------------------------------------
__global__ __launch_bounds__(64) void finalize_kernel(const float* __restrict__ sums,
                                                      const float* __restrict__ gamma,
                                                      const float* __restrict__ beta,
                                                      float* __restrict__ scaleshift) {
    const int f = threadIdx.x;
    const float inv_n = 1.0f / (float)N_NODES;
    float mean = sums[f] * inv_n;
    float var = sums[64 + f] * inv_n - mean * mean;
    float sc = gamma[f] * rsqrtf(var + 1e-5f);
    scaleshift[f] = sc;
    scaleshift[64 + f] = beta[f] - mean * sc;
}

// ---------------------------------------------------------------------------
// Threefry-2x32, 20 rounds, key=(0,42). Hand-verified vs JAX test vector.
// ---------------------------------------------------------------------------
__device__ __forceinline__ uint32_t rotl32(uint32_t x, int d) {
    return (x << d) | (x >> (32 - d));
}

__device__ __forceinline__ void threefry2x32_0_42(uint32_t x0, uint32_t x1,
                                                  uint32_t& o0, uint32_t& o1) {
    const uint32_t k0 = 0u, k1 = 42u;
    const uint32_t k2 = k0 ^ k1 ^ 0x1BD11BDAu;
    x0 += k0; x1 += k1;
    x0 += x1; x1 = rotl32(x1, 13) ^ x0;
    x0 += x1; x1 = rotl32(x1, 15) ^ x0;
    x0 += x1; x1 = rotl32(x1, 26) ^ x0;
    x0 += x1; x1 = rotl32(x1, 6)  ^ x0;
    x0 += k1; x1 += k2 + 1u;
    x0 += x1; x1 = rotl32(x1, 17) ^ x0;
    x0 += x1; x1 = rotl32(x1, 29) ^ x0;
    x0 += x1; x1 = rotl32(x1, 16) ^ x0;
    x0 += x1; x1 = rotl32(x1, 24) ^ x0;
    x0 += k2; x1 += k0 + 2u;
    x0 += x1; x1 = rotl32(x1, 13) ^ x0;
    x0 += x1; x1 = rotl32(x1, 15) ^ x0;
    x0 += x1; x1 = rotl32(x1, 26) ^ x0;
    x0 += x1; x1 = rotl32(x1, 6)  ^ x0;
    x0 += k0; x1 += k1 + 3u;
    x0 += x1; x1 = rotl32(x1, 17) ^ x0;
    x0 += x1; x1 = rotl32(x1, 29) ^ x0;
    x0 += x1; x1 = rotl32(x1, 16) ^ x0;
    x0 += x1; x1 = rotl32(x1, 24) ^ x0;
    x0 += k1; x1 += k2 + 4u;
    x0 += x1; x1 = rotl32(x1, 13) ^ x0;
    x0 += x1; x1 = rotl32(x1, 15) ^ x0;
    x0 += x1; x1 = rotl32(x1, 26) ^ x0;
    x0 += x1; x1 = rotl32(x1, 6)  ^ x0;
    x0 += k2; x1 += k0 + 5u;
    o0 = x0; o1 = x1;
}

// ---------------------------------------------------------------------------
// Apply: BN affine + ReLU + dropout; f32 out (overwrites dead support).
// ---------------------------------------------------------------------------
__global__ __launch_bounds__(256) void apply_kernel(const float* __restrict__ agg,
                                                    const float* __restrict__ scaleshift,
                                                    float* __restrict__ out) {
    const int i = blockIdx.x * 256 + threadIdx.x;
    if (i >= N_ELEMS) return;
    const int f = i & 63;
    const float sc = scaleshift[f];
    const float sh = scaleshift[64 + f];

    uint32_t o0, o1;
    threefry2x32_0_42(0u, (uint32_t)i, o0, o1);
    uint32_t bits = o0 ^ o1;
    float u = __uint_as_float((bits >> 9) | 0x3F800000u) - 1.0f;

    float v = fmaxf(fmaf(agg[i], sc, sh), 0.0f);
    out[i] = (u < 0.7f) ? v * (1.0f / 0.7f) : 0.0f;
}

// ---------------------------------------------------------------------------
extern "C" void kernel_launch(void* const* d_in, const int* in_sizes, int n_in,
                              void* d_out, int out_size, void* d_ws, size_t ws_size,
                              hipStream_t stream) {
    const float* x     = (const float*)d_in[0];
    const int*   row   = (const int*)d_in[1];
    const int*   col   = (const int*)d_in[2];
    const float* ew    = (const float*)d_in[3];
    const float* W     = (const float*)d_in[4];
    const float* gamma = (const float*)d_in[6];
    const float* beta  = (const float*)d_in[7];
    float* out = (float*)d_out;

    float* sums       = (float*)d_ws;                      // 128 f32
    int*   hb         = (int*)(sums + 128);                // 1024 i32 (782 used)
    float* scaleshift = (float*)(hb + 1024);               // 128 f32
    int*   bbase      = (int*)(scaleshift + 128);          // 1024 i32
    int*   bcur       = bbase + 1024;                      // 1024 i32
    int*   rowptr     = bcur + 1024;                       // 100004 i32
    unsigned short* wt = (unsigned short*)(rowptr + 100004); // 16384 ushort
    float* agg        = (float*)(wt + 16384);              // 6.4M f32
    int2*  sorted     = (int2*)(agg + (size_t)N_ELEMS);    // 1.6M int2
    unsigned short* support = (unsigned short*)out;        // 6.4M bf16, in d_out
    int2*  bucketed   = (int2*)agg;                        // aliases agg (dead)

    // zero sums + hb (adjacent)
    hipMemsetAsync(d_ws, 0, (size_t)(128 + 1024) * 4, stream);

    wtprep_kernel<<<64, 256, 0, stream>>>(W, wt);
    gemm_kernel<<<(N_NODES + 63) / 64, 256, 0, stream>>>(x, wt, support);

    bhist_kernel<<<NBBLK, 256, 0, stream>>>(row, hb);
    bscan_kernel<<<1, 1024, 0, stream>>>(hb, bbase, bcur, rowptr);
    bucket_kernel<<<NBBLK, 256, 0, stream>>>(row, col, ew, bcur, bucketed);
    place_kernel<<<NBUCK, 256, 0, stream>>>(bbase, hb, bucketed, sorted, rowptr);

    gather_kernel<<<GBLK, 256, 0, stream>>>(rowptr, sorted, support, agg, sums);

    finalize_kernel<<<1, 64, 0, stream>>>(sums, gamma, beta, scaleshift);
    apply_kernel<<<(N_ELEMS + 255) / 256, 256, 0, stream>>>(agg, scaleshift, out);
}